// Round 1
// baseline (47.687 us; speedup 1.0000x reference)
//
#include <hip/hip_runtime.h>

#define B_ 64
#define M_ 4096
#define D_ 128
#define O_ 16

// Pass 1: u[b,o,k] = sum_d x1[b,d]*W[o,d,k] + v2[o,k];  c[b,o] = x1[b].v1[o] + bias[o]
__global__ __launch_bounds__(128) void prep_kernel(
    const float* __restrict__ x1, const float* __restrict__ W,
    const float* __restrict__ V, const float* __restrict__ bias,
    float* __restrict__ u, float* __restrict__ c)
{
    const int o = blockIdx.x;   // [0,16)
    const int b = blockIdx.y;   // [0,64)
    const int k = threadIdx.x;  // [0,128)
    __shared__ float x1s[D_];
    __shared__ float red[2];
    x1s[k] = x1[b * D_ + k];
    __syncthreads();

    const float* Wo = W + o * D_ * D_;
    float acc = 0.f;
    #pragma unroll 8
    for (int d = 0; d < D_; ++d)
        acc = fmaf(x1s[d], Wo[d * D_ + k], acc);   // coalesced over k

    u[(b * O_ + o) * D_ + k] = acc + V[o * 2 * D_ + D_ + k];  // + v2[o,k]

    // c[b,o] = sum_k x1[b,k]*v1[o,k] + bias[o]
    float p = x1s[k] * V[o * 2 * D_ + k];
    #pragma unroll
    for (int off = 32; off; off >>= 1) p += __shfl_down(p, off, 64);
    if ((k & 63) == 0) red[k >> 6] = p;
    __syncthreads();
    if (k == 0) c[b * O_ + o] = red[0] + red[1] + bias[o];
}

// Pass 2: out[b,m,o] = relu( sum_k x2[b,m,k]*u[b,o,k] + c[b,o] )
__global__ __launch_bounds__(256) void fused_kernel(
    const float* __restrict__ x2, const float* __restrict__ u,
    const float* __restrict__ c, float* __restrict__ out)
{
    const int b = blockIdx.y;
    const int m = blockIdx.x * 256 + threadIdx.x;

    __shared__ float us[O_ * D_];   // 8 KB: u[b] tile
    __shared__ float cs[O_];
    {
        const float4* u4 = (const float4*)(u + b * O_ * D_);
        float4* s4 = (float4*)us;
        #pragma unroll
        for (int i = 0; i < (O_ * D_ / 4) / 256; ++i)     // 512 float4 / 256 thr = 2
            s4[threadIdx.x + i * 256] = u4[threadIdx.x + i * 256];
        if (threadIdx.x < O_) cs[threadIdx.x] = c[b * O_ + threadIdx.x];
    }
    __syncthreads();

    const float4* xr = (const float4*)(x2 + ((size_t)(b * M_ + m)) * D_);
    float acc[O_];
    #pragma unroll
    for (int o = 0; o < O_; ++o) acc[o] = cs[o];

    #pragma unroll 4
    for (int kk = 0; kk < D_ / 4; ++kk) {
        float4 xv = xr[kk];
        #pragma unroll
        for (int o = 0; o < O_; ++o) {
            const float* up = &us[o * D_ + kk * 4];   // wave-uniform addr -> LDS broadcast
            acc[o] = fmaf(xv.x, up[0], acc[o]);
            acc[o] = fmaf(xv.y, up[1], acc[o]);
            acc[o] = fmaf(xv.z, up[2], acc[o]);
            acc[o] = fmaf(xv.w, up[3], acc[o]);
        }
    }

    float4* op = (float4*)(out + ((size_t)(b * M_ + m)) * O_);
    #pragma unroll
    for (int q = 0; q < 4; ++q) {
        float4 r;
        r.x = fmaxf(acc[q * 4 + 0], 0.f);
        r.y = fmaxf(acc[q * 4 + 1], 0.f);
        r.z = fmaxf(acc[q * 4 + 2], 0.f);
        r.w = fmaxf(acc[q * 4 + 3], 0.f);
        op[q] = r;
    }
}

extern "C" void kernel_launch(void* const* d_in, const int* in_sizes, int n_in,
                              void* d_out, int out_size, void* d_ws, size_t ws_size,
                              hipStream_t stream) {
    const float* x1   = (const float*)d_in[0];
    const float* x2   = (const float*)d_in[1];
    const float* W    = (const float*)d_in[2];
    const float* V    = (const float*)d_in[3];
    const float* bias = (const float*)d_in[4];
    float* out = (float*)d_out;

    float* u = (float*)d_ws;                 // B*O*D floats = 512 KB
    float* c = u + B_ * O_ * D_;             // B*O floats

    prep_kernel<<<dim3(O_, B_), 128, 0, stream>>>(x1, W, V, bias, u, c);
    fused_kernel<<<dim3(M_ / 256, B_), 256, 0, stream>>>(x2, u, c, out);
}